// Round 5
// baseline (232.944 us; speedup 1.0000x reference)
//
#include <hip/hip_runtime.h>
#include <hip/hip_fp16.h>

#define IN_F 24
#define HID 64
#define NB 512      // dst buckets (node ranges)
#define NPB 256     // partition blocks (edge slices)
#define GSZ_MAX 256 // max nodes per bucket (ceil(100000/512) = 196)
#define PBUF 7168   // pair capacity per bucket in LDS (mean ~6250, +11 sigma)
#define SRC_BITS 17 // src < 100000 < 2^17; loc < 196 < 2^8

typedef unsigned int u32;

// bucket of node d:  k = floor(d*NB/n)
// node range of bucket b (exact inverse):  [ceil(b*n/NB), ceil((b+1)*n/NB))
__device__ __forceinline__ int bucket_lo(int b, int n) {
    return (int)(((long long)b * n + NB - 1) / NB);
}

// ---------------- pass 1a: per-(slice,bucket) histogram ----------------
__global__ __launch_bounds__(256) void k_pcount(const int* __restrict__ dst,
                                                u32* __restrict__ pc, int e, int n) {
    __shared__ u32 h[NB];
    for (int j = threadIdx.x; j < NB; j += 256) h[j] = 0;
    __syncthreads();
    int blk = blockIdx.x;
    long long begin = (long long)e * blk / NPB;
    long long end   = (long long)e * (blk + 1) / NPB;
    for (long long i = begin + threadIdx.x; i < end; i += 256) {
        int k = (int)((long long)dst[i] * NB / n);
        atomicAdd(&h[k], 1u);
    }
    __syncthreads();
    for (int j = threadIdx.x; j < NB; j += 256) pc[(size_t)blk * NB + j] = h[j];
}

// ---------------- pass 1b-parallel: per-column exclusive scan (NPB=256 rows) ----------------
__global__ __launch_bounds__(256) void k_pscan_a(u32* __restrict__ pc,
                                                 u32* __restrict__ colsum) {
    __shared__ u32 ps[256];
    int t = blockIdx.x;   // column (bucket)
    int tid = threadIdx.x;
    u32 v = pc[(size_t)tid * NB + t];
    ps[tid] = v;
    __syncthreads();
    for (int off = 1; off < 256; off <<= 1) {
        u32 v2 = (tid >= off) ? ps[tid - off] : 0;
        __syncthreads();
        ps[tid] += v2;
        __syncthreads();
    }
    pc[(size_t)tid * NB + t] = ps[tid] - v;   // exclusive within-column
    if (tid == 255) colsum[t] = ps[255];
}

// exclusive scan of the 512 column sums -> bucket bases
__global__ void k_pscan_b(const u32* __restrict__ colsum, u32* __restrict__ basep) {
    __shared__ u32 s[NB];
    int t = threadIdx.x;
    u32 v = colsum[t];
    s[t] = v;
    __syncthreads();
    for (int off = 1; off < NB; off <<= 1) {
        u32 v2 = (t >= off) ? s[t - off] : 0;
        __syncthreads();
        s[t] += v2;
        __syncthreads();
    }
    basep[t] = s[t] - v;
}

// ---------------- pass 1c: direct scatter of packed (loc<<17|src) into bucket order ----------------
__global__ __launch_bounds__(256) void k_part(const int* __restrict__ src,
                                              const int* __restrict__ dst,
                                              const u32* __restrict__ pc,
                                              const u32* __restrict__ basep,
                                              u32* __restrict__ pairs, int e, int n) {
    __shared__ u32 cur[NB];
    int blk = (blockIdx.x & 7) * (NPB / 8) + (blockIdx.x >> 3);  // XCD-affine (perf heuristic)
    for (int j = threadIdx.x; j < NB; j += 256)
        cur[j] = pc[(size_t)blk * NB + j] + basep[j];
    __syncthreads();
    long long begin = (long long)e * blk / NPB;
    long long end   = (long long)e * (blk + 1) / NPB;
    for (long long i = begin + threadIdx.x; i < end; i += 256) {
        int d = dst[i];
        int sv = src[i];
        int k = (int)((long long)d * NB / n);
        u32 loc = (u32)(d - bucket_lo(k, n));
        u32 pos = atomicAdd(&cur[k], 1u);
        pairs[pos] = (loc << SRC_BITS) | (u32)sv;
    }
}

// ---------------- pass 2: per-bucket mini-CSR in LDS (+ fused xs f16 pack, 2 planes) ----------------
// R4: xs split into two 24-B planes (feats 0..11 / 12..23), each 2.4 MB -> each fits
// per-XCD L2 (4 MB) during its own aggregate pass (R3 diagnosis: 4.8 MB table thrashed
// L2, 55% of gather lines went to L3; FETCH 84 MB).
__global__ __launch_bounds__(256) void k_bucket(const u32* __restrict__ pairs,
                                                const u32* __restrict__ basep,
                                                const float* __restrict__ x,
                                                int* __restrict__ cnt,
                                                int* __restrict__ row_start,
                                                float* __restrict__ dinv,
                                                int* __restrict__ csr_src,
                                                __half2* __restrict__ xs2, int e, int n) {
    __shared__ u32 pbuf[PBUF];
    __shared__ u32 h[GSZ_MAX];
    __shared__ u32 cur[GSZ_MAX];
    __shared__ u32 sc[GSZ_MAX];
    __shared__ float dloc[GSZ_MAX];
    int b = blockIdx.x;
    int lo = bucket_lo(b, n);
    int hi = bucket_lo(b + 1, n);
    int gsz = hi - lo;               // <= GSZ_MAX
    u32 start = basep[b];
    u32 endp = (b + 1 < NB) ? basep[b + 1] : (u32)e;
    int nbp = (int)(endp - start);
    for (int j = threadIdx.x; j < GSZ_MAX; j += 256) h[j] = 0;
    __syncthreads();
    int stored = nbp < PBUF ? nbp : PBUF;
    for (int i = threadIdx.x; i < stored; i += 256) {
        u32 p = pairs[start + i];
        pbuf[i] = p;
        atomicAdd(&h[p >> SRC_BITS], 1u);
    }
    for (int i = PBUF + threadIdx.x; i < nbp; i += 256) {  // overflow path (rare)
        atomicAdd(&h[pairs[start + i] >> SRC_BITS], 1u);
    }
    __syncthreads();
    int t = threadIdx.x;
    u32 v = h[t];
    sc[t] = v;
    __syncthreads();
    for (int off = 1; off < 256; off <<= 1) {
        u32 v2 = (t >= off) ? sc[t - off] : 0;
        __syncthreads();
        sc[t] += v2;
        __syncthreads();
    }
    u32 excl = sc[t] - v;
    if (t < gsz) {
        float dv = rsqrtf((float)(v + 1));  // +1 self-loop
        cnt[lo + t] = (int)v;
        row_start[lo + t] = (int)(start + excl);
        dinv[lo + t] = dv;
        dloc[t] = dv;
        cur[t] = excl;
    }
    __syncthreads();
    for (int i = threadIdx.x; i < stored; i += 256) {
        u32 p = pbuf[i];
        u32 pos = atomicAdd(&cur[p >> SRC_BITS], 1u);
        csr_src[start + pos] = (int)(p & ((1u << SRC_BITS) - 1));
    }
    for (int i = PBUF + threadIdx.x; i < nbp; i += 256) {
        u32 p = pairs[start + i];
        u32 pos = atomicAdd(&cur[p >> SRC_BITS], 1u);
        csr_src[start + pos] = (int)(p & ((1u << SRC_BITS) - 1));
    }
    // fused pack: plane0[i][0..5] = f16(x[i][0..11]*dinv), plane1[i][0..5] = feats 12..23
    const float2* xf = (const float2*)(x + (long long)lo * IN_F);
    for (int i = threadIdx.x; i < gsz * 12; i += 256) {
        float2 vv = xf[i];
        int nd = i / 12;
        int u = i - nd * 12;
        float dn = dloc[nd];
        __half2 hv = __floats2half2_rn(vv.x * dn, vv.y * dn);
        long long rowbase = (long long)(lo + nd) * 6;
        if (u < 6) xs2[rowbase + u] = hv;
        else       xs2[(long long)n * 6 + rowbase + (u - 6)] = hv;
    }
}

// ---------------- shared gather-accumulate core (4-lane groups, 3 active, uint2/lane) ----------------
// 24-B rows: lane f4 (0..2) loads 8 B = feats 4f4..4f4+3 of its half-plane.
__device__ __forceinline__ void gather_acc(const uint2* __restrict__ xq,
                                           const int* __restrict__ cp0, int c, int f4,
                                           float& AX0, float& AY0, float& AX1, float& AY1) {
    float a0 = 0.0f, b0 = 0.0f, c0 = 0.0f, d0 = 0.0f;
    float a1 = 0.0f, b1v = 0.0f, c1 = 0.0f, d1 = 0.0f;
    int j = 0;
    for (; j + 16 <= c; j += 16) {
        const int* cp = cp0 + j;
        int s[16];
#pragma unroll
        for (int t = 0; t < 16; ++t) s[t] = cp[t];
        uint2 u[16];
#pragma unroll
        for (int t = 0; t < 16; ++t) u[t] = xq[(size_t)((u32)s[t] * 3u + (u32)f4)];
#pragma unroll
        for (int t = 0; t < 16; t += 2) {
            float2 e0 = __half22float2(__builtin_bit_cast(__half2, u[t].x));
            float2 e1 = __half22float2(__builtin_bit_cast(__half2, u[t].y));
            float2 o0 = __half22float2(__builtin_bit_cast(__half2, u[t + 1].x));
            float2 o1 = __half22float2(__builtin_bit_cast(__half2, u[t + 1].y));
            a0 += e0.x; b0 += e0.y; c0 += e1.x; d0 += e1.y;
            a1 += o0.x; b1v += o0.y; c1 += o1.x; d1 += o1.y;
        }
    }
    for (; j + 8 <= c; j += 8) {
        const int* cp = cp0 + j;
        int s[8];
#pragma unroll
        for (int t = 0; t < 8; ++t) s[t] = cp[t];
        uint2 u[8];
#pragma unroll
        for (int t = 0; t < 8; ++t) u[t] = xq[(size_t)((u32)s[t] * 3u + (u32)f4)];
#pragma unroll
        for (int t = 0; t < 8; t += 2) {
            float2 e0 = __half22float2(__builtin_bit_cast(__half2, u[t].x));
            float2 e1 = __half22float2(__builtin_bit_cast(__half2, u[t].y));
            float2 o0 = __half22float2(__builtin_bit_cast(__half2, u[t + 1].x));
            float2 o1 = __half22float2(__builtin_bit_cast(__half2, u[t + 1].y));
            a0 += e0.x; b0 += e0.y; c0 += e1.x; d0 += e1.y;
            a1 += o0.x; b1v += o0.y; c1 += o1.x; d1 += o1.y;
        }
    }
    for (; j < c; ++j) {
        int s = cp0[j];
        uint2 u = xq[(size_t)((u32)s * 3u + (u32)f4)];
        float2 e0 = __half22float2(__builtin_bit_cast(__half2, u.x));
        float2 e1 = __half22float2(__builtin_bit_cast(__half2, u.y));
        a0 += e0.x; b0 += e0.y; c0 += e1.x; d0 += e1.y;
    }
    AX0 = a0 + a1; AY0 = b0 + b1v; AX1 = c0 + c1; AY1 = d0 + d1;
}

// ---------------- R4 pass A: aggregate feats 0..11 (plane0 hot, L2-resident) -> a0 ----------------
__global__ __launch_bounds__(256) void k_agg_p0(const uint2* __restrict__ xq0,
                                                const float* __restrict__ x,
                                                const float* __restrict__ dinv,
                                                const int* __restrict__ row_start,
                                                const int* __restrict__ cnt,
                                                const int* __restrict__ csr_src,
                                                float* __restrict__ a0, int n) {
    int g = threadIdx.x >> 2;        // 64 groups of 4 lanes
    int f4 = threadIdx.x & 3;        // gather-active: 0..2
    int node = blockIdx.x * 64 + g;
    if (node >= n) return;
    if (f4 >= 3) return;             // pass A has no Phase B; idle lanes exit
    float dn = dinv[node];
    float ax0, ay0, ax1, ay1;
    gather_acc(xq0, csr_src + row_start[node], cnt[node], f4, ax0, ay0, ax1, ay1);
    float4 sx4 = *(const float4*)(x + (long long)node * IN_F + 4 * f4);
    float4 r;
    r.x = (ax0 + sx4.x * dn) * dn;
    r.y = (ay0 + sx4.y * dn) * dn;
    r.z = (ax1 + sx4.z * dn) * dn;
    r.w = (ay1 + sx4.w * dn) * dn;
    ((float4*)(a0 + (long long)node * 12))[f4] = r;
}

// ---------------- R4 pass B: aggregate feats 12..23 (plane1 hot) + Phase B + layer-2 lin ----------------
__global__ __launch_bounds__(256) void k_agg_p1(const uint2* __restrict__ xq1,
                                                const float* __restrict__ x,
                                                const float* __restrict__ dinv,
                                                const int* __restrict__ row_start,
                                                const int* __restrict__ cnt,
                                                const int* __restrict__ csr_src,
                                                const float* __restrict__ a0,
                                                const float* __restrict__ W1,
                                                const float* __restrict__ b1,
                                                const float* __restrict__ W2,
                                                float* __restrict__ zs, int n) {
    __shared__ float w[IN_F * HID];   // k-major: w[k*64+f]
    __shared__ float w2s[HID];
    __shared__ float b1s[HID];
    for (int j = threadIdx.x; j < IN_F * HID; j += 256) w[j] = W1[j];
    if (threadIdx.x < HID) { w2s[threadIdx.x] = W2[threadIdx.x]; b1s[threadIdx.x] = b1[threadIdx.x]; }
    __syncthreads();   // weights only; no further barriers
    int g = threadIdx.x >> 2;        // 64 groups of 4 lanes
    int f4 = threadIdx.x & 3;        // gather-active: 0..2
    int node = blockIdx.x * 64 + g;
    if (node >= n) return;
    float dn = dinv[node];
    float ax0 = 0.0f, ay0 = 0.0f, ax1 = 0.0f, ay1 = 0.0f;
    float4 old = make_float4(0.0f, 0.0f, 0.0f, 0.0f);
    if (f4 < 3) {
        gather_acc(xq1, csr_src + row_start[node], cnt[node], f4, ax0, ay0, ax1, ay1);
        float4 sx4 = *(const float4*)(x + (long long)node * IN_F + 12 + 4 * f4);
        ax0 = (ax0 + sx4.x * dn) * dn;
        ay0 = (ay0 + sx4.y * dn) * dn;
        ax1 = (ax1 + sx4.z * dn) * dn;
        ay1 = (ay1 + sx4.w * dn) * dn;
        old = ((const float4*)(a0 + (long long)node * 12))[f4];
    }
    // ---- Phase B: dense transform; feats broadcast via width-4 shuffle ----
    int fb = f4 * 16;                 // 16 hidden units per lane (4 lanes x 16 = 64)
    float h[16];
#pragma unroll
    for (int jj = 0; jj < 16; ++jj) h[jj] = b1s[fb + jj];
#pragma unroll
    for (int k = 0; k < 12; ++k) {    // feats 0..11 from a0 (float4 per source lane)
        int sl = k >> 2;
        int r = k & 3;
        float xv;
        if (r == 0)      xv = __shfl(old.x, sl, 4);
        else if (r == 1) xv = __shfl(old.y, sl, 4);
        else if (r == 2) xv = __shfl(old.z, sl, 4);
        else             xv = __shfl(old.w, sl, 4);
        const float* wr = w + k * HID + fb;
#pragma unroll
        for (int jj = 0; jj < 16; ++jj) h[jj] += xv * wr[jj];
    }
#pragma unroll
    for (int k = 0; k < 12; ++k) {    // feats 12..23 from this pass's gather
        int sl = k >> 2;
        int r = k & 3;
        float xv;
        if (r == 0)      xv = __shfl(ax0, sl, 4);
        else if (r == 1) xv = __shfl(ay0, sl, 4);
        else if (r == 2) xv = __shfl(ax1, sl, 4);
        else             xv = __shfl(ay1, sl, 4);
        const float* wr = w + (12 + k) * HID + fb;
#pragma unroll
        for (int jj = 0; jj < 16; ++jj) h[jj] += xv * wr[jj];
    }
    float p = 0.0f;
#pragma unroll
    for (int jj = 0; jj < 16; ++jj) p += fmaxf(h[jj], 0.0f) * w2s[fb + jj];
    p += __shfl_down(p, 2, 4);
    p += __shfl_down(p, 1, 4);
    if (f4 == 0) zs[node] = p * dn;
}

// ---------------- layer 2 gather: 16-lane group per node ----------------
__global__ void k_out(const float* __restrict__ zs, const float* __restrict__ dinv,
                      const int* __restrict__ row_start, const int* __restrict__ cnt,
                      const int* __restrict__ csr_src, const float* __restrict__ b2,
                      float* __restrict__ out, int n) {
    int t = blockIdx.x * blockDim.x + threadIdx.x;
    int node = t >> 4;
    int lane = t & 15;
    if (node >= n) return;
    int row = row_start[node];
    int c = cnt[node];
    float v = 0.0f;
    for (int j = lane; j < c; j += 16) {
        v += zs[csr_src[row + j]];
    }
    v += __shfl_down(v, 8, 16);
    v += __shfl_down(v, 4, 16);
    v += __shfl_down(v, 2, 16);
    v += __shfl_down(v, 1, 16);
    if (lane == 0) {
        out[node] = b2[0] + dinv[node] * (zs[node] + v);
    }
}

extern "C" void kernel_launch(void* const* d_in, const int* in_sizes, int n_in,
                              void* d_out, int out_size, void* d_ws, size_t ws_size,
                              hipStream_t stream) {
    const float* x   = (const float*)d_in[0];
    const int*   ei  = (const int*)d_in[1];
    const float* W1  = (const float*)d_in[2];
    const float* b1  = (const float*)d_in[3];
    const float* W2  = (const float*)d_in[4];
    const float* b2  = (const float*)d_in[5];
    float* out = (float*)d_out;

    const int n = in_sizes[0] / IN_F;      // 100000
    const int e = in_sizes[1] / 2;         // 3200000
    const int* src = ei;
    const int* dst = ei + e;

    const int B = 256;

    // workspace layout. pairs (u32, CSR build) overlays {zs, a0} (lifetimes disjoint).
    // xs written by k_bucket while other blocks still read pairs -> OUTSIDE the overlay.
    char* base = (char*)d_ws;
    u32* pairs     = (u32*)base;                        // e u32 (12.8 MB)
    float* zs      = (float*)base;                      // n f32              [overlay]
    size_t zsb = ((size_t)n * 4 + 255) & ~(size_t)255;
    float* a0      = (float*)(base + zsb);              // n*12 f32 (4.8 MB)  [overlay]
    size_t ov = ((size_t)e * 4 + 255) & ~(size_t)255;
    char* after    = base + ov;
    int* cnt       = (int*)after;
    int* row_start = cnt + n;
    int* csr_src   = row_start + n;                     // e ints (12.8 MB)
    float* dinv    = (float*)(csr_src + e);
    __half* xs     = (__half*)(dinv + n);               // 2 planes x n*12 f16 (4.8 MB total)
    u32* pc        = (u32*)(xs + (size_t)n * IN_F);     // NPB*NB u32 (0.5 MB)
    u32* colsum    = pc + (size_t)NPB * NB;             // NB u32
    u32* basep     = colsum + NB;                       // NB u32

    const uint2* xq0 = (const uint2*)xs;                    // plane0: feats 0..11
    const uint2* xq1 = (const uint2*)(xs + (size_t)n * 12); // plane1: feats 12..23

    // CSR build: single-read two-level bucket sort (no device-scope atomics)
    k_pcount<<<NPB, B, 0, stream>>>(dst, pc, e, n);
    k_pscan_a<<<NB, B, 0, stream>>>(pc, colsum);
    k_pscan_b<<<1, NB, 0, stream>>>(colsum, basep);
    k_part<<<NPB, B, 0, stream>>>(src, dst, pc, basep, pairs, e, n);
    k_bucket<<<NB, B, 0, stream>>>(pairs, basep, x, cnt, row_start, dinv, csr_src,
                                   (__half2*)xs, e, n);

    // fused layer-1 aggregate, feature-split into two L2-resident passes (R4)
    const int nblk = (n + 63) / 64;
    k_agg_p0<<<nblk, B, 0, stream>>>(xq0, x, dinv, row_start, cnt, csr_src, a0, n);
    k_agg_p1<<<nblk, B, 0, stream>>>(xq1, x, dinv, row_start, cnt, csr_src, a0,
                                     W1, b1, W2, zs, n);

    // layer 2: gather zs (16 lanes/node)
    const long long n16 = (long long)n * 16;
    k_out<<<(int)((n16 + B - 1) / B), B, 0, stream>>>(zs, dinv, row_start, cnt, csr_src, b2, out, n);
}

// Round 6
// 215.444 us; speedup vs baseline: 1.0812x; 1.0812x over previous
//
#include <hip/hip_runtime.h>
#include <hip/hip_fp16.h>

#define IN_F 24
#define HID 64
#define NB 512      // dst buckets (node ranges)
#define NPB 256     // partition blocks (edge slices)
#define GSZ_MAX 256 // max nodes per bucket (ceil(100000/512) = 196)
#define PBUF 7168   // pair capacity per bucket in LDS (mean ~6250, +11 sigma)
#define SRC_BITS 17 // src < 100000 < 2^17; loc < 196 < 2^8

typedef unsigned int u32;

// bucket of node d:  k = floor(d*NB/n)
// node range of bucket b (exact inverse):  [ceil(b*n/NB), ceil((b+1)*n/NB))
__device__ __forceinline__ int bucket_lo(int b, int n) {
    return (int)(((long long)b * n + NB - 1) / NB);
}

// ---------------- pass 1a: per-(slice,bucket) histogram ----------------
__global__ __launch_bounds__(256) void k_pcount(const int* __restrict__ dst,
                                                u32* __restrict__ pc, int e, int n) {
    __shared__ u32 h[NB];
    for (int j = threadIdx.x; j < NB; j += 256) h[j] = 0;
    __syncthreads();
    int blk = blockIdx.x;
    long long begin = (long long)e * blk / NPB;
    long long end   = (long long)e * (blk + 1) / NPB;
    for (long long i = begin + threadIdx.x; i < end; i += 256) {
        int k = (int)((long long)dst[i] * NB / n);
        atomicAdd(&h[k], 1u);
    }
    __syncthreads();
    for (int j = threadIdx.x; j < NB; j += 256) pc[(size_t)blk * NB + j] = h[j];
}

// ---------------- pass 1b-parallel: per-column exclusive scan (NPB=256 rows) ----------------
__global__ __launch_bounds__(256) void k_pscan_a(u32* __restrict__ pc,
                                                 u32* __restrict__ colsum) {
    __shared__ u32 ps[256];
    int t = blockIdx.x;   // column (bucket)
    int tid = threadIdx.x;
    u32 v = pc[(size_t)tid * NB + t];
    ps[tid] = v;
    __syncthreads();
    for (int off = 1; off < 256; off <<= 1) {
        u32 v2 = (tid >= off) ? ps[tid - off] : 0;
        __syncthreads();
        ps[tid] += v2;
        __syncthreads();
    }
    pc[(size_t)tid * NB + t] = ps[tid] - v;   // exclusive within-column
    if (tid == 255) colsum[t] = ps[255];
}

// exclusive scan of the 512 column sums -> bucket bases
__global__ void k_pscan_b(const u32* __restrict__ colsum, u32* __restrict__ basep) {
    __shared__ u32 s[NB];
    int t = threadIdx.x;
    u32 v = colsum[t];
    s[t] = v;
    __syncthreads();
    for (int off = 1; off < NB; off <<= 1) {
        u32 v2 = (t >= off) ? s[t - off] : 0;
        __syncthreads();
        s[t] += v2;
        __syncthreads();
    }
    basep[t] = s[t] - v;
}

// ---------------- pass 1c: direct scatter of packed (loc<<17|src) into bucket order ----------------
__global__ __launch_bounds__(256) void k_part(const int* __restrict__ src,
                                              const int* __restrict__ dst,
                                              const u32* __restrict__ pc,
                                              const u32* __restrict__ basep,
                                              u32* __restrict__ pairs, int e, int n) {
    __shared__ u32 cur[NB];
    int blk = (blockIdx.x & 7) * (NPB / 8) + (blockIdx.x >> 3);  // XCD-affine (perf heuristic)
    for (int j = threadIdx.x; j < NB; j += 256)
        cur[j] = pc[(size_t)blk * NB + j] + basep[j];
    __syncthreads();
    long long begin = (long long)e * blk / NPB;
    long long end   = (long long)e * (blk + 1) / NPB;
    for (long long i = begin + threadIdx.x; i < end; i += 256) {
        int d = dst[i];
        int sv = src[i];
        int k = (int)((long long)d * NB / n);
        u32 loc = (u32)(d - bucket_lo(k, n));
        u32 pos = atomicAdd(&cur[k], 1u);
        pairs[pos] = (loc << SRC_BITS) | (u32)sv;
    }
}

// ---------------- pass 2: per-bucket mini-CSR in LDS (+ fused xs f16 pack, 48 B rows) ----------------
// R5 post-mortem: feature-split two-pass (L2 residency attempt) REGRESSED +15us
// (csr/a0 streams share L2, no residency materialized; extra pass overhead). Reverted
// to R3 single-table 48-B rows; added zero sentinel row at xs[n] for R6 masked tail.
__global__ __launch_bounds__(256) void k_bucket(const u32* __restrict__ pairs,
                                                const u32* __restrict__ basep,
                                                const float* __restrict__ x,
                                                int* __restrict__ cnt,
                                                int* __restrict__ row_start,
                                                float* __restrict__ dinv,
                                                int* __restrict__ csr_src,
                                                __half2* __restrict__ xs2, int e, int n) {
    __shared__ u32 pbuf[PBUF];
    __shared__ u32 h[GSZ_MAX];
    __shared__ u32 cur[GSZ_MAX];
    __shared__ u32 sc[GSZ_MAX];
    __shared__ float dloc[GSZ_MAX];
    int b = blockIdx.x;
    // zero sentinel row at index n (read by masked final-batch slots in k_agg_hz)
    if (b == 0 && threadIdx.x < 12)
        xs2[(long long)n * 12 + threadIdx.x] = __floats2half2_rn(0.0f, 0.0f);
    int lo = bucket_lo(b, n);
    int hi = bucket_lo(b + 1, n);
    int gsz = hi - lo;               // <= GSZ_MAX
    u32 start = basep[b];
    u32 endp = (b + 1 < NB) ? basep[b + 1] : (u32)e;
    int nbp = (int)(endp - start);
    for (int j = threadIdx.x; j < GSZ_MAX; j += 256) h[j] = 0;
    __syncthreads();
    int stored = nbp < PBUF ? nbp : PBUF;
    for (int i = threadIdx.x; i < stored; i += 256) {
        u32 p = pairs[start + i];
        pbuf[i] = p;
        atomicAdd(&h[p >> SRC_BITS], 1u);
    }
    for (int i = PBUF + threadIdx.x; i < nbp; i += 256) {  // overflow path (rare)
        atomicAdd(&h[pairs[start + i] >> SRC_BITS], 1u);
    }
    __syncthreads();
    int t = threadIdx.x;
    u32 v = h[t];
    sc[t] = v;
    __syncthreads();
    for (int off = 1; off < 256; off <<= 1) {
        u32 v2 = (t >= off) ? sc[t - off] : 0;
        __syncthreads();
        sc[t] += v2;
        __syncthreads();
    }
    u32 excl = sc[t] - v;
    if (t < gsz) {
        float dv = rsqrtf((float)(v + 1));  // +1 self-loop
        cnt[lo + t] = (int)v;
        row_start[lo + t] = (int)(start + excl);
        dinv[lo + t] = dv;
        dloc[t] = dv;
        cur[t] = excl;
    }
    __syncthreads();
    for (int i = threadIdx.x; i < stored; i += 256) {
        u32 p = pbuf[i];
        u32 pos = atomicAdd(&cur[p >> SRC_BITS], 1u);
        csr_src[start + pos] = (int)(p & ((1u << SRC_BITS) - 1));
    }
    for (int i = PBUF + threadIdx.x; i < nbp; i += 256) {
        u32 p = pairs[start + i];
        u32 pos = atomicAdd(&cur[p >> SRC_BITS], 1u);
        csr_src[start + pos] = (int)(p & ((1u << SRC_BITS) - 1));
    }
    // fused pack: xs[i][f] = f16(x[i][f] * dinv[i]) for this bucket's nodes (contiguous)
    const float2* xf = (const float2*)(x + (long long)lo * IN_F);
    for (int i = threadIdx.x; i < gsz * 12; i += 256) {
        float2 vv = xf[i];
        float dn = dloc[i / 12];
        xs2[(long long)lo * 12 + i] = __floats2half2_rn(vv.x * dn, vv.y * dn);
    }
}

// ---------------- fused layer-1 aggregate + transform + layer-2 lin (barrier-free) ----------------
// R3 structure (8-lane groups, uint2 gathers: best measured, agg=49us).
// R6: ragged tail (8-loop + scalar chain) replaced by ONE masked sentinel batch of 16
// -> every group runs exactly ceil(c/16) fully-parallel batches; wave-max convergence.
// Mask cost is per-NODE (~32 VALU-ops), not per-batch (R1's mistake).
__global__ __launch_bounds__(256) void k_agg_hz(const float* __restrict__ x,
                                                const __half2* __restrict__ xs2,
                                                const float* __restrict__ dinv,
                                                const int* __restrict__ row_start,
                                                const int* __restrict__ cnt,
                                                const int* __restrict__ csr_src,
                                                const float* __restrict__ W1,
                                                const float* __restrict__ b1,
                                                const float* __restrict__ W2,
                                                float* __restrict__ zs, int n) {
    __shared__ float w[IN_F * HID];   // k-major: w[k*64+f]
    __shared__ float w2s[HID];
    __shared__ float b1s[HID];
    for (int j = threadIdx.x; j < IN_F * HID; j += 256) w[j] = W1[j];
    if (threadIdx.x < HID) { w2s[threadIdx.x] = W2[threadIdx.x]; b1s[threadIdx.x] = b1[threadIdx.x]; }
    __syncthreads();   // weights only; no further barriers
    int g = threadIdx.x >> 3;        // 32 groups of 8 lanes
    int f4 = threadIdx.x & 7;        // 0..7; gather-active: 0..5
    int node = blockIdx.x * 32 + g;
    if (node >= n) return;
    float dn = dinv[node];
    const uint2* xq = (const uint2*)xs2;   // row r -> xq[r*6 + f4], 48 B rows
    // ---- Phase A: gather-aggregate into registers (lanes 0..5 of each group) ----
    float ax0 = 0.0f, ay0 = 0.0f, ax1 = 0.0f, ay1 = 0.0f;
    if (f4 < 6) {
        int row = row_start[node];
        int c = cnt[node];
        // 8 independent accumulator chains (even/odd slots)
        float a0 = 0.0f, b0 = 0.0f, c0 = 0.0f, d0 = 0.0f;
        float a1 = 0.0f, b1v = 0.0f, c1 = 0.0f, d1 = 0.0f;
        int j = 0;
        for (; j + 16 <= c; j += 16) {
            const int* cp = csr_src + row + j;
            int s[16];
#pragma unroll
            for (int t = 0; t < 16; ++t) s[t] = cp[t];
            uint2 u[16];
#pragma unroll
            for (int t = 0; t < 16; ++t) u[t] = xq[(size_t)((u32)s[t] * 6u + (u32)f4)];
#pragma unroll
            for (int t = 0; t < 16; t += 2) {
                float2 e0 = __half22float2(__builtin_bit_cast(__half2, u[t].x));
                float2 e1 = __half22float2(__builtin_bit_cast(__half2, u[t].y));
                float2 o0 = __half22float2(__builtin_bit_cast(__half2, u[t + 1].x));
                float2 o1 = __half22float2(__builtin_bit_cast(__half2, u[t + 1].y));
                a0 += e0.x; b0 += e0.y; c0 += e1.x; d0 += e1.y;
                a1 += o0.x; b1v += o0.y; c1 += o1.x; d1 += o1.y;
            }
        }
        if (j < c) {   // masked final batch: sentinel row n absorbs t >= rem slots
            const int* cp = csr_src + row + j;   // over-read <=15 ints lands in dinv region (in-workspace)
            int rem = c - j;                      // 1..15
            int s[16];
#pragma unroll
            for (int t = 0; t < 16; ++t) {
                int tmp = cp[t];
                s[t] = (t < rem) ? tmp : n;
            }
            uint2 u[16];
#pragma unroll
            for (int t = 0; t < 16; ++t) u[t] = xq[(size_t)((u32)s[t] * 6u + (u32)f4)];
#pragma unroll
            for (int t = 0; t < 16; t += 2) {
                float2 e0 = __half22float2(__builtin_bit_cast(__half2, u[t].x));
                float2 e1 = __half22float2(__builtin_bit_cast(__half2, u[t].y));
                float2 o0 = __half22float2(__builtin_bit_cast(__half2, u[t + 1].x));
                float2 o1 = __half22float2(__builtin_bit_cast(__half2, u[t + 1].y));
                a0 += e0.x; b0 += e0.y; c0 += e1.x; d0 += e1.y;
                a1 += o0.x; b1v += o0.y; c1 += o1.x; d1 += o1.y;
            }
        }
        ax0 = a0 + a1; ay0 = b0 + b1v; ax1 = c0 + c1; ay1 = d0 + d1;
        // self-loop (float4: feats 4f4..4f4+3, 16-B aligned)
        float4 sx4 = *(const float4*)(x + (long long)node * IN_F + 4 * f4);
        ax0 = (ax0 + sx4.x * dn) * dn;
        ay0 = (ay0 + sx4.y * dn) * dn;
        ax1 = (ax1 + sx4.z * dn) * dn;
        ay1 = (ay1 + sx4.w * dn) * dn;
    }
    // ---- Phase B: dense transform; feats broadcast via width-8 shuffle ----
    int fb = f4 * 8;                  // 8 hidden units per lane (8 lanes x 8 = 64)
    float h[8];
#pragma unroll
    for (int jj = 0; jj < 8; ++jj) h[jj] = b1s[fb + jj];
#pragma unroll
    for (int k = 0; k < IN_F; ++k) {
        int sl = k >> 2;              // source lane 0..5
        int r = k & 3;
        float xv;
        if (r == 0)      xv = __shfl(ax0, sl, 8);
        else if (r == 1) xv = __shfl(ay0, sl, 8);
        else if (r == 2) xv = __shfl(ax1, sl, 8);
        else             xv = __shfl(ay1, sl, 8);
        const float* wr = w + k * HID + fb;
#pragma unroll
        for (int jj = 0; jj < 8; ++jj) h[jj] += xv * wr[jj];
    }
    float p = 0.0f;
#pragma unroll
    for (int jj = 0; jj < 8; ++jj) p += fmaxf(h[jj], 0.0f) * w2s[fb + jj];
    p += __shfl_down(p, 4, 8);
    p += __shfl_down(p, 2, 8);
    p += __shfl_down(p, 1, 8);
    if (f4 == 0) zs[node] = p * dn;
}

// ---------------- layer 2 gather: 16-lane group per node ----------------
__global__ void k_out(const float* __restrict__ zs, const float* __restrict__ dinv,
                      const int* __restrict__ row_start, const int* __restrict__ cnt,
                      const int* __restrict__ csr_src, const float* __restrict__ b2,
                      float* __restrict__ out, int n) {
    int t = blockIdx.x * blockDim.x + threadIdx.x;
    int node = t >> 4;
    int lane = t & 15;
    if (node >= n) return;
    int row = row_start[node];
    int c = cnt[node];
    float v = 0.0f;
    for (int j = lane; j < c; j += 16) {
        v += zs[csr_src[row + j]];
    }
    v += __shfl_down(v, 8, 16);
    v += __shfl_down(v, 4, 16);
    v += __shfl_down(v, 2, 16);
    v += __shfl_down(v, 1, 16);
    if (lane == 0) {
        out[node] = b2[0] + dinv[node] * (zs[node] + v);
    }
}

extern "C" void kernel_launch(void* const* d_in, const int* in_sizes, int n_in,
                              void* d_out, int out_size, void* d_ws, size_t ws_size,
                              hipStream_t stream) {
    const float* x   = (const float*)d_in[0];
    const int*   ei  = (const int*)d_in[1];
    const float* W1  = (const float*)d_in[2];
    const float* b1  = (const float*)d_in[3];
    const float* W2  = (const float*)d_in[4];
    const float* b2  = (const float*)d_in[5];
    float* out = (float*)d_out;

    const int n = in_sizes[0] / IN_F;      // 100000
    const int e = in_sizes[1] / 2;         // 3200000
    const int* src = ei;
    const int* dst = ei + e;

    const int B = 256;

    // workspace layout. pairs (u32, CSR build) overlays zs (lifetimes disjoint).
    // xs written by k_bucket while other blocks still read pairs -> OUTSIDE the overlay.
    char* base = (char*)d_ws;
    u32* pairs     = (u32*)base;                        // e u32 (12.8 MB)
    float* zs      = (float*)base;                      // n f32              [overlay]
    size_t ov = ((size_t)e * 4 + 255) & ~(size_t)255;
    char* after    = base + ov;
    int* cnt       = (int*)after;
    int* row_start = cnt + n;
    int* csr_src   = row_start + n;                     // e ints (12.8 MB)
    float* dinv    = (float*)(csr_src + e);
    __half* xs     = (__half*)(dinv + n);               // (n+1)*24 f16 (4.8 MB), sentinel row at n
    u32* pc        = (u32*)(xs + (size_t)(n + 1) * IN_F); // NPB*NB u32 (0.5 MB)
    u32* colsum    = pc + (size_t)NPB * NB;             // NB u32
    u32* basep     = colsum + NB;                       // NB u32

    // CSR build: single-read two-level bucket sort (no device-scope atomics)
    k_pcount<<<NPB, B, 0, stream>>>(dst, pc, e, n);
    k_pscan_a<<<NB, B, 0, stream>>>(pc, colsum);
    k_pscan_b<<<1, NB, 0, stream>>>(colsum, basep);
    k_part<<<NPB, B, 0, stream>>>(src, dst, pc, basep, pairs, e, n);
    k_bucket<<<NB, B, 0, stream>>>(pairs, basep, x, cnt, row_start, dinv, csr_src,
                                   (__half2*)xs, e, n);

    // fused layer-1 aggregate + transform (+ layer-2 linear) -> zs (barrier-free)
    k_agg_hz<<<(n + 31) / 32, B, 0, stream>>>(x, (const __half2*)xs, dinv,
                                              row_start, cnt, csr_src,
                                              W1, b1, W2, zs, n);

    // layer 2: gather zs (16 lanes/node)
    const long long n16 = (long long)n * 16;
    k_out<<<(int)((n16 + B - 1) / B), B, 0, stream>>>(zs, dinv, row_start, cnt, csr_src, b2, out, n);
}

// Round 7
// 195.396 us; speedup vs baseline: 1.1922x; 1.1026x over previous
//
#include <hip/hip_runtime.h>
#include <hip/hip_fp16.h>

#define IN_F 24
#define HID 64
#define NB 512      // dst buckets (node ranges)
#define NPB 256     // partition blocks (edge slices)
#define GSZ_MAX 256 // max nodes per bucket (ceil(100000/512) = 196)
#define PBUF 7168   // pair capacity per bucket in LDS (mean ~6250, +11 sigma)
#define SRC_BITS 17 // src < 100000 < 2^17; loc < 196 < 2^8

typedef unsigned int u32;

// bucket of node d:  k = floor(d*NB/n)
// node range of bucket b (exact inverse):  [ceil(b*n/NB), ceil((b+1)*n/NB))
__device__ __forceinline__ int bucket_lo(int b, int n) {
    return (int)(((long long)b * n + NB - 1) / NB);
}

// ---------------- pass 1a: per-(slice,bucket) histogram ----------------
// R7: 1024-thread blocks (was 256 -> 1 block/CU = 12.5% occupancy; latency-starved)
__global__ __launch_bounds__(1024) void k_pcount(const int* __restrict__ dst,
                                                 u32* __restrict__ pc, int e, int n) {
    __shared__ u32 h[NB];
    for (int j = threadIdx.x; j < NB; j += 1024) h[j] = 0;
    __syncthreads();
    int blk = blockIdx.x;
    long long begin = (long long)e * blk / NPB;
    long long end   = (long long)e * (blk + 1) / NPB;
    for (long long i = begin + threadIdx.x; i < end; i += 1024) {
        int k = (int)((long long)dst[i] * NB / n);
        atomicAdd(&h[k], 1u);
    }
    __syncthreads();
    for (int j = threadIdx.x; j < NB; j += 1024) pc[(size_t)blk * NB + j] = h[j];
}

// ---------------- pass 1b-parallel: per-column exclusive scan (NPB=256 rows) ----------------
__global__ __launch_bounds__(256) void k_pscan_a(u32* __restrict__ pc,
                                                 u32* __restrict__ colsum) {
    __shared__ u32 ps[256];
    int t = blockIdx.x;   // column (bucket)
    int tid = threadIdx.x;
    u32 v = pc[(size_t)tid * NB + t];
    ps[tid] = v;
    __syncthreads();
    for (int off = 1; off < 256; off <<= 1) {
        u32 v2 = (tid >= off) ? ps[tid - off] : 0;
        __syncthreads();
        ps[tid] += v2;
        __syncthreads();
    }
    pc[(size_t)tid * NB + t] = ps[tid] - v;   // exclusive within-column
    if (tid == 255) colsum[t] = ps[255];
}

// exclusive scan of the 512 column sums -> bucket bases
__global__ void k_pscan_b(const u32* __restrict__ colsum, u32* __restrict__ basep) {
    __shared__ u32 s[NB];
    int t = threadIdx.x;
    u32 v = colsum[t];
    s[t] = v;
    __syncthreads();
    for (int off = 1; off < NB; off <<= 1) {
        u32 v2 = (t >= off) ? s[t - off] : 0;
        __syncthreads();
        s[t] += v2;
        __syncthreads();
    }
    basep[t] = s[t] - v;
}

// ---------------- pass 1c: direct scatter of packed (loc<<17|src) into bucket order ----------------
// R7: 1024-thread blocks (4x waves/CU for scattered-write latency hiding)
__global__ __launch_bounds__(1024) void k_part(const int* __restrict__ src,
                                               const int* __restrict__ dst,
                                               const u32* __restrict__ pc,
                                               const u32* __restrict__ basep,
                                               u32* __restrict__ pairs, int e, int n) {
    __shared__ u32 cur[NB];
    int blk = (blockIdx.x & 7) * (NPB / 8) + (blockIdx.x >> 3);  // XCD-affine (perf heuristic)
    for (int j = threadIdx.x; j < NB; j += 1024)
        cur[j] = pc[(size_t)blk * NB + j] + basep[j];
    __syncthreads();
    long long begin = (long long)e * blk / NPB;
    long long end   = (long long)e * (blk + 1) / NPB;
    for (long long i = begin + threadIdx.x; i < end; i += 1024) {
        int d = dst[i];
        int sv = src[i];
        int k = (int)((long long)d * NB / n);
        u32 loc = (u32)(d - bucket_lo(k, n));
        u32 pos = atomicAdd(&cur[k], 1u);
        pairs[pos] = (loc << SRC_BITS) | (u32)sv;
    }
}

// ---------------- pass 2: per-bucket mini-CSR in LDS (+ fused xs f16 pack, 48 B rows) ----------------
// R7: 512-thread blocks (16 waves/CU; scan phase guarded to first 256 lanes).
__global__ __launch_bounds__(512) void k_bucket(const u32* __restrict__ pairs,
                                                const u32* __restrict__ basep,
                                                const float* __restrict__ x,
                                                int* __restrict__ cnt,
                                                int* __restrict__ row_start,
                                                float* __restrict__ dinv,
                                                int* __restrict__ csr_src,
                                                __half2* __restrict__ xs2, int e, int n) {
    __shared__ u32 pbuf[PBUF];
    __shared__ u32 h[GSZ_MAX];
    __shared__ u32 cur[GSZ_MAX];
    __shared__ u32 sc[GSZ_MAX];
    __shared__ float dloc[GSZ_MAX];
    int b = blockIdx.x;
    // zero sentinel row at index n (read by masked final-batch slots in k_agg_hz)
    if (b == 0 && threadIdx.x < 12)
        xs2[(long long)n * 12 + threadIdx.x] = __floats2half2_rn(0.0f, 0.0f);
    int lo = bucket_lo(b, n);
    int hi = bucket_lo(b + 1, n);
    int gsz = hi - lo;               // <= GSZ_MAX
    u32 start = basep[b];
    u32 endp = (b + 1 < NB) ? basep[b + 1] : (u32)e;
    int nbp = (int)(endp - start);
    for (int j = threadIdx.x; j < GSZ_MAX; j += 512) h[j] = 0;
    __syncthreads();
    int stored = nbp < PBUF ? nbp : PBUF;
    for (int i = threadIdx.x; i < stored; i += 512) {
        u32 p = pairs[start + i];
        pbuf[i] = p;
        atomicAdd(&h[p >> SRC_BITS], 1u);
    }
    for (int i = PBUF + threadIdx.x; i < nbp; i += 512) {  // overflow path (rare)
        atomicAdd(&h[pairs[start + i] >> SRC_BITS], 1u);
    }
    __syncthreads();
    int t = threadIdx.x;
    u32 v = 0;
    if (t < GSZ_MAX) { v = h[t]; sc[t] = v; }
    __syncthreads();
    for (int off = 1; off < GSZ_MAX; off <<= 1) {
        u32 v2 = (t >= off && t < GSZ_MAX) ? sc[t - off] : 0;
        __syncthreads();
        if (t < GSZ_MAX) sc[t] += v2;
        __syncthreads();
    }
    u32 excl = (t < GSZ_MAX) ? (sc[t] - v) : 0;
    if (t < gsz) {
        float dv = rsqrtf((float)(v + 1));  // +1 self-loop
        cnt[lo + t] = (int)v;
        row_start[lo + t] = (int)(start + excl);
        dinv[lo + t] = dv;
        dloc[t] = dv;
        cur[t] = excl;
    }
    __syncthreads();
    for (int i = threadIdx.x; i < stored; i += 512) {
        u32 p = pbuf[i];
        u32 pos = atomicAdd(&cur[p >> SRC_BITS], 1u);
        csr_src[start + pos] = (int)(p & ((1u << SRC_BITS) - 1));
    }
    for (int i = PBUF + threadIdx.x; i < nbp; i += 512) {
        u32 p = pairs[start + i];
        u32 pos = atomicAdd(&cur[p >> SRC_BITS], 1u);
        csr_src[start + pos] = (int)(p & ((1u << SRC_BITS) - 1));
    }
    // fused pack: xs[i][f] = f16(x[i][f] * dinv[i]) for this bucket's nodes (contiguous)
    const float2* xf = (const float2*)(x + (long long)lo * IN_F);
    for (int i = threadIdx.x; i < gsz * 12; i += 512) {
        float2 vv = xf[i];
        float dn = dloc[i / 12];
        xs2[(long long)lo * 12 + i] = __floats2half2_rn(vv.x * dn, vv.y * dn);
    }
}

// ---------------- fused layer-1 aggregate + transform + layer-2 lin (barrier-free) ----------------
// R3 structure (8-lane groups, uint2 gathers) + R6 masked sentinel tail. Best measured.
__global__ __launch_bounds__(256) void k_agg_hz(const float* __restrict__ x,
                                                const __half2* __restrict__ xs2,
                                                const float* __restrict__ dinv,
                                                const int* __restrict__ row_start,
                                                const int* __restrict__ cnt,
                                                const int* __restrict__ csr_src,
                                                const float* __restrict__ W1,
                                                const float* __restrict__ b1,
                                                const float* __restrict__ W2,
                                                float* __restrict__ zs, int n) {
    __shared__ float w[IN_F * HID];   // k-major: w[k*64+f]
    __shared__ float w2s[HID];
    __shared__ float b1s[HID];
    for (int j = threadIdx.x; j < IN_F * HID; j += 256) w[j] = W1[j];
    if (threadIdx.x < HID) { w2s[threadIdx.x] = W2[threadIdx.x]; b1s[threadIdx.x] = b1[threadIdx.x]; }
    __syncthreads();   // weights only; no further barriers
    int g = threadIdx.x >> 3;        // 32 groups of 8 lanes
    int f4 = threadIdx.x & 7;        // 0..7; gather-active: 0..5
    int node = blockIdx.x * 32 + g;
    if (node >= n) return;
    float dn = dinv[node];
    const uint2* xq = (const uint2*)xs2;   // row r -> xq[r*6 + f4], 48 B rows
    // ---- Phase A: gather-aggregate into registers (lanes 0..5 of each group) ----
    float ax0 = 0.0f, ay0 = 0.0f, ax1 = 0.0f, ay1 = 0.0f;
    if (f4 < 6) {
        int row = row_start[node];
        int c = cnt[node];
        // 8 independent accumulator chains (even/odd slots)
        float a0 = 0.0f, b0 = 0.0f, c0 = 0.0f, d0 = 0.0f;
        float a1 = 0.0f, b1v = 0.0f, c1 = 0.0f, d1 = 0.0f;
        int j = 0;
        for (; j + 16 <= c; j += 16) {
            const int* cp = csr_src + row + j;
            int s[16];
#pragma unroll
            for (int t = 0; t < 16; ++t) s[t] = cp[t];
            uint2 u[16];
#pragma unroll
            for (int t = 0; t < 16; ++t) u[t] = xq[(size_t)((u32)s[t] * 6u + (u32)f4)];
#pragma unroll
            for (int t = 0; t < 16; t += 2) {
                float2 e0 = __half22float2(__builtin_bit_cast(__half2, u[t].x));
                float2 e1 = __half22float2(__builtin_bit_cast(__half2, u[t].y));
                float2 o0 = __half22float2(__builtin_bit_cast(__half2, u[t + 1].x));
                float2 o1 = __half22float2(__builtin_bit_cast(__half2, u[t + 1].y));
                a0 += e0.x; b0 += e0.y; c0 += e1.x; d0 += e1.y;
                a1 += o0.x; b1v += o0.y; c1 += o1.x; d1 += o1.y;
            }
        }
        if (j < c) {   // masked final batch: sentinel row n absorbs t >= rem slots
            const int* cp = csr_src + row + j;   // over-read <=15 ints lands in dinv region (in-workspace)
            int rem = c - j;                      // 1..15
            int s[16];
#pragma unroll
            for (int t = 0; t < 16; ++t) {
                int tmp = cp[t];
                s[t] = (t < rem) ? tmp : n;
            }
            uint2 u[16];
#pragma unroll
            for (int t = 0; t < 16; ++t) u[t] = xq[(size_t)((u32)s[t] * 6u + (u32)f4)];
#pragma unroll
            for (int t = 0; t < 16; t += 2) {
                float2 e0 = __half22float2(__builtin_bit_cast(__half2, u[t].x));
                float2 e1 = __half22float2(__builtin_bit_cast(__half2, u[t].y));
                float2 o0 = __half22float2(__builtin_bit_cast(__half2, u[t + 1].x));
                float2 o1 = __half22float2(__builtin_bit_cast(__half2, u[t + 1].y));
                a0 += e0.x; b0 += e0.y; c0 += e1.x; d0 += e1.y;
                a1 += o0.x; b1v += o0.y; c1 += o1.x; d1 += o1.y;
            }
        }
        ax0 = a0 + a1; ay0 = b0 + b1v; ax1 = c0 + c1; ay1 = d0 + d1;
        // self-loop (float4: feats 4f4..4f4+3, 16-B aligned)
        float4 sx4 = *(const float4*)(x + (long long)node * IN_F + 4 * f4);
        ax0 = (ax0 + sx4.x * dn) * dn;
        ay0 = (ay0 + sx4.y * dn) * dn;
        ax1 = (ax1 + sx4.z * dn) * dn;
        ay1 = (ay1 + sx4.w * dn) * dn;
    }
    // ---- Phase B: dense transform; feats broadcast via width-8 shuffle ----
    int fb = f4 * 8;                  // 8 hidden units per lane (8 lanes x 8 = 64)
    float h[8];
#pragma unroll
    for (int jj = 0; jj < 8; ++jj) h[jj] = b1s[fb + jj];
#pragma unroll
    for (int k = 0; k < IN_F; ++k) {
        int sl = k >> 2;              // source lane 0..5
        int r = k & 3;
        float xv;
        if (r == 0)      xv = __shfl(ax0, sl, 8);
        else if (r == 1) xv = __shfl(ay0, sl, 8);
        else if (r == 2) xv = __shfl(ax1, sl, 8);
        else             xv = __shfl(ay1, sl, 8);
        const float* wr = w + k * HID + fb;
#pragma unroll
        for (int jj = 0; jj < 8; ++jj) h[jj] += xv * wr[jj];
    }
    float p = 0.0f;
#pragma unroll
    for (int jj = 0; jj < 8; ++jj) p += fmaxf(h[jj], 0.0f) * w2s[fb + jj];
    p += __shfl_down(p, 4, 8);
    p += __shfl_down(p, 2, 8);
    p += __shfl_down(p, 1, 8);
    if (f4 == 0) zs[node] = p * dn;
}

// ---------------- layer 2 gather: 16-lane group per node ----------------
__global__ void k_out(const float* __restrict__ zs, const float* __restrict__ dinv,
                      const int* __restrict__ row_start, const int* __restrict__ cnt,
                      const int* __restrict__ csr_src, const float* __restrict__ b2,
                      float* __restrict__ out, int n) {
    int t = blockIdx.x * blockDim.x + threadIdx.x;
    int node = t >> 4;
    int lane = t & 15;
    if (node >= n) return;
    int row = row_start[node];
    int c = cnt[node];
    float v = 0.0f;
    for (int j = lane; j < c; j += 16) {
        v += zs[csr_src[row + j]];
    }
    v += __shfl_down(v, 8, 16);
    v += __shfl_down(v, 4, 16);
    v += __shfl_down(v, 2, 16);
    v += __shfl_down(v, 1, 16);
    if (lane == 0) {
        out[node] = b2[0] + dinv[node] * (zs[node] + v);
    }
}

extern "C" void kernel_launch(void* const* d_in, const int* in_sizes, int n_in,
                              void* d_out, int out_size, void* d_ws, size_t ws_size,
                              hipStream_t stream) {
    const float* x   = (const float*)d_in[0];
    const int*   ei  = (const int*)d_in[1];
    const float* W1  = (const float*)d_in[2];
    const float* b1  = (const float*)d_in[3];
    const float* W2  = (const float*)d_in[4];
    const float* b2  = (const float*)d_in[5];
    float* out = (float*)d_out;

    const int n = in_sizes[0] / IN_F;      // 100000
    const int e = in_sizes[1] / 2;         // 3200000
    const int* src = ei;
    const int* dst = ei + e;

    const int B = 256;

    // workspace layout. pairs (u32, CSR build) overlays zs (lifetimes disjoint).
    // xs written by k_bucket while other blocks still read pairs -> OUTSIDE the overlay.
    char* base = (char*)d_ws;
    u32* pairs     = (u32*)base;                        // e u32 (12.8 MB)
    float* zs      = (float*)base;                      // n f32              [overlay]
    size_t ov = ((size_t)e * 4 + 255) & ~(size_t)255;
    char* after    = base + ov;
    int* cnt       = (int*)after;
    int* row_start = cnt + n;
    int* csr_src   = row_start + n;                     // e ints (12.8 MB)
    float* dinv    = (float*)(csr_src + e);
    __half* xs     = (__half*)(dinv + n);               // (n+1)*24 f16 (4.8 MB), sentinel row at n
    u32* pc        = (u32*)(xs + (size_t)(n + 1) * IN_F); // NPB*NB u32 (0.5 MB)
    u32* colsum    = pc + (size_t)NPB * NB;             // NB u32
    u32* basep     = colsum + NB;                       // NB u32

    // CSR build: single-read two-level bucket sort (no device-scope atomics)
    k_pcount<<<NPB, 1024, 0, stream>>>(dst, pc, e, n);
    k_pscan_a<<<NB, B, 0, stream>>>(pc, colsum);
    k_pscan_b<<<1, NB, 0, stream>>>(colsum, basep);
    k_part<<<NPB, 1024, 0, stream>>>(src, dst, pc, basep, pairs, e, n);
    k_bucket<<<NB, 512, 0, stream>>>(pairs, basep, x, cnt, row_start, dinv, csr_src,
                                     (__half2*)xs, e, n);

    // fused layer-1 aggregate + transform (+ layer-2 linear) -> zs (barrier-free)
    k_agg_hz<<<(n + 31) / 32, B, 0, stream>>>(x, (const __half2*)xs, dinv,
                                              row_start, cnt, csr_src,
                                              W1, b1, W2, zs, n);

    // layer 2: gather zs (16 lanes/node)
    const long long n16 = (long long)n * 16;
    k_out<<<(int)((n16 + B - 1) / B), B, 0, stream>>>(zs, dinv, row_start, cnt, csr_src, b2, out, n);
}